// Round 2
// baseline (1203.260 us; speedup 1.0000x reference)
//
#include <hip/hip_runtime.h>

// Problem constants (B=16, N=4096, C=64, O=64, D=16, K=3)
#define NN 4096
#define DD 16
#define BB 16
#define CC 64
#define OO 64
#define BC 1024   // BB*CC

// ---------------------------------------------------------------------------
// Kernel 1: A = softmax(relu(E @ E^T), axis=1). One 256-thread block per row.
// Each thread owns 16 strided columns held in registers (single global write).
// ---------------------------------------------------------------------------
__global__ __launch_bounds__(256) void softmax_adj(const float* __restrict__ E,
                                                   float* __restrict__ A) {
    const int i = blockIdx.x;
    const int t = threadIdx.x;
    __shared__ float esh[DD];
    __shared__ float redm[4], reds[4];
    if (t < DD) esh[t] = E[i * DD + t];
    __syncthreads();
    float er[DD];
#pragma unroll
    for (int d = 0; d < DD; ++d) er[d] = esh[d];

    float v[16];
    float m = 0.0f;  // relu => max >= 0
#pragma unroll
    for (int s = 0; s < 16; ++s) {
        const int j = s * 256 + t;
        const float4* ej = (const float4*)(E + j * DD);
        float4 a0 = ej[0], a1 = ej[1], a2 = ej[2], a3 = ej[3];
        float dot = a0.x * er[0] + a0.y * er[1] + a0.z * er[2] + a0.w * er[3]
                  + a1.x * er[4] + a1.y * er[5] + a1.z * er[6] + a1.w * er[7]
                  + a2.x * er[8] + a2.y * er[9] + a2.z * er[10] + a2.w * er[11]
                  + a3.x * er[12] + a3.y * er[13] + a3.z * er[14] + a3.w * er[15];
        v[s] = fmaxf(dot, 0.0f);
        m = fmaxf(m, v[s]);
    }
    // block max
#pragma unroll
    for (int off = 1; off < 64; off <<= 1) m = fmaxf(m, __shfl_xor(m, off));
    const int wave = t >> 6, lane = t & 63;
    if (lane == 0) redm[wave] = m;
    __syncthreads();
    m = fmaxf(fmaxf(redm[0], redm[1]), fmaxf(redm[2], redm[3]));

    float sum = 0.0f;
#pragma unroll
    for (int s = 0; s < 16; ++s) {
        v[s] = expf(v[s] - m);
        sum += v[s];
    }
#pragma unroll
    for (int off = 1; off < 64; off <<= 1) sum += __shfl_xor(sum, off);
    if (lane == 0) reds[wave] = sum;
    __syncthreads();
    const float rinv = 1.0f / (reds[0] + reds[1] + reds[2] + reds[3]);
#pragma unroll
    for (int s = 0; s < 16; ++s) A[(size_t)i * NN + s * 256 + t] = v[s] * rinv;
}

// ---------------------------------------------------------------------------
// Kernel 2: pack X [B,N,C] -> Xt [N, B*C]  (float4 granularity)
// ---------------------------------------------------------------------------
__global__ __launch_bounds__(256) void pack_x(const float* __restrict__ X,
                                              float* __restrict__ Xt) {
    const int idx = blockIdx.x * 256 + threadIdx.x;  // over NN*BC/4 float4s
    const int cq = idx & 15;
    const int b = (idx >> 4) & 15;
    const int n = idx >> 8;
    // per-batch float4 stride = N*C/4 = 65536
    float4 v = ((const float4*)X)[(size_t)b * 65536 + n * (CC / 4) + cq];
    ((float4*)Xt)[idx] = v;
}

// ---------------------------------------------------------------------------
// Kernel 3: fp32 GEMM  C[4096,1024] = A[4096,4096] @ B[4096,1024]
// 256 threads, tile 128x64, BK=16, 8x4 microtile/thread. grid (16, 32).
// ---------------------------------------------------------------------------
#define GBM 128
#define GBN 64
#define GBK 16
__global__ __launch_bounds__(256) void gemm_f32(const float* __restrict__ A,
                                                const float* __restrict__ B,
                                                float* __restrict__ C) {
    const int Kd = NN, Nc = BC;
    __shared__ float As[GBK][GBM + 4];  // transposed: As[k][m]
    __shared__ float Bs[GBK][GBN + 4];  // Bs[k][n]
    const int t = threadIdx.x;
    const int tx = t & 15;   // 4-col group
    const int ty = t >> 4;   // 8-row group
    const int row0 = blockIdx.y * GBM;
    const int col0 = blockIdx.x * GBN;

    float acc[8][4];
#pragma unroll
    for (int i = 0; i < 8; ++i)
#pragma unroll
        for (int j = 0; j < 4; ++j) acc[i][j] = 0.0f;

    for (int kt = 0; kt < Kd; kt += GBK) {
        // A tile: 128x16 = 512 float4, 2 per thread, transpose into As
#pragma unroll
        for (int l = 0; l < 2; ++l) {
            const int idx = t + l * 256;
            const int ar = idx >> 2;
            const int ac = (idx & 3) * 4;
            float4 v = *(const float4*)(A + (size_t)(row0 + ar) * Kd + kt + ac);
            As[ac + 0][ar] = v.x;
            As[ac + 1][ar] = v.y;
            As[ac + 2][ar] = v.z;
            As[ac + 3][ar] = v.w;
        }
        // B tile: 16x64 = 256 float4, 1 per thread
        {
            const int br = t >> 4;
            const int bc = (t & 15) * 4;
            float4 v = *(const float4*)(B + (size_t)(kt + br) * Nc + col0 + bc);
            *(float4*)&Bs[br][bc] = v;
        }
        __syncthreads();
#pragma unroll
        for (int kk = 0; kk < GBK; ++kk) {
            float a[8], b[4];
            *(float4*)&a[0] = *(const float4*)&As[kk][ty * 8];
            *(float4*)&a[4] = *(const float4*)&As[kk][ty * 8 + 4];
            *(float4*)&b[0] = *(const float4*)&Bs[kk][tx * 4];
#pragma unroll
            for (int i = 0; i < 8; ++i)
#pragma unroll
                for (int j = 0; j < 4; ++j) acc[i][j] += a[i] * b[j];
        }
        __syncthreads();
    }
#pragma unroll
    for (int i = 0; i < 8; ++i) {
        float4 v = make_float4(acc[i][0], acc[i][1], acc[i][2], acc[i][3]);
        *(float4*)(C + (size_t)(row0 + ty * 8 + i) * Nc + col0 + tx * 4) = v;
    }
}

// ---------------------------------------------------------------------------
// Kernel 4: per-node W build + apply + bias. One block per node.
//   W[k,i,o] = sum_d E[n,d] * wp[d,k,i,o]           (48KB LDS)
//   out[b,n,o] = sum_{k,i} xg[k][b,i] * W[k,i,o] + sum_d E[n,d]*bp[d,o]
//   xg[0]=X, xg[1]=G1, xg[2]=2*G2-X
// ---------------------------------------------------------------------------
__global__ __launch_bounds__(256) void final_apply(const float* __restrict__ X,
                                                   const float* __restrict__ E,
                                                   const float* __restrict__ G1,
                                                   const float* __restrict__ G2,
                                                   const float* __restrict__ wp,
                                                   const float* __restrict__ bp,
                                                   float* __restrict__ out) {
    const int n = blockIdx.x;
    const int t = threadIdx.x;
    __shared__ float W[3 * CC * OO];   // 48KB
    __shared__ float xg[3][BC];        // 12KB
    __shared__ float esh[DD];
    if (t < DD) esh[t] = E[n * DD + t];
    // stage xg
#pragma unroll
    for (int l = 0; l < 4; ++l) {
        const int idx = t + l * 256;       // (b,i): b=idx>>6, i=idx&63
        const int b = idx >> 6;
        const int i = idx & 63;
        const float xs = X[(size_t)b * (NN * CC) + (size_t)n * CC + i];
        const float g1 = G1[(size_t)n * BC + idx];
        const float g2 = G2[(size_t)n * BC + idx];
        xg[0][idx] = xs;
        xg[1][idx] = g1;
        xg[2][idx] = 2.0f * g2 - xs;
    }
    __syncthreads();
    float er[DD];
#pragma unroll
    for (int d = 0; d < DD; ++d) er[d] = esh[d];

    // W generation: 3*64*64 = 12288 floats = 3072 float4
    const float4* wp4 = (const float4*)wp;
#pragma unroll
    for (int l = 0; l < 12; ++l) {
        const int w4 = t + l * 256;
        float4 a = make_float4(0.f, 0.f, 0.f, 0.f);
#pragma unroll
        for (int d = 0; d < DD; ++d) {
            float4 v = wp4[d * 3072 + w4];
            a.x += er[d] * v.x;
            a.y += er[d] * v.y;
            a.z += er[d] * v.z;
            a.w += er[d] * v.w;
        }
        *(float4*)&W[w4 * 4] = a;
    }
    __syncthreads();

    // apply: each thread does 4 (b,o) pairs; a full wave shares b (broadcast xg)
#pragma unroll
    for (int p = 0; p < 4; ++p) {
        const int idx2 = t + p * 256;
        const int b = idx2 >> 6;
        const int o = idx2 & 63;
        float acc = 0.0f;
#pragma unroll
        for (int d = 0; d < DD; ++d) acc += er[d] * bp[d * OO + o];
#pragma unroll
        for (int k = 0; k < 3; ++k) {
            const float* wk = &W[k * (CC * OO) + o];
            const float* xk = &xg[k][b * CC];
#pragma unroll 16
            for (int i = 0; i < CC; ++i) acc += xk[i] * wk[i * OO];
        }
        out[(size_t)b * (NN * OO) + (size_t)n * OO + o] = acc;
    }
}

// ---------------------------------------------------------------------------
extern "C" void kernel_launch(void* const* d_in, const int* in_sizes, int n_in,
                              void* d_out, int out_size, void* d_ws, size_t ws_size,
                              hipStream_t stream) {
    const float* X  = (const float*)d_in[0];   // [16,4096,64]
    const float* E  = (const float*)d_in[1];   // [4096,16]
    // d_in[2] = E_t (unused, Temb=False)
    const float* wp = (const float*)d_in[3];   // [16,3,64,64]
    const float* bp = (const float*)d_in[4];   // [16,64]
    float* out = (float*)d_out;                // [16,4096,64]

    float* A  = (float*)d_ws;                  // 4096*4096      = 64MB
    float* Xt = A  + (size_t)NN * NN;          // 4096*1024      = 16MB
    float* G1 = Xt + (size_t)NN * BC;          // 4096*1024      = 16MB
    float* G2 = Xt;                            // overlay: Xt dead after GEMM1

    softmax_adj<<<NN, 256, 0, stream>>>(E, A);
    pack_x<<<(NN * BC / 4) / 256, 256, 0, stream>>>(X, Xt);
    gemm_f32<<<dim3(BC / GBN, NN / GBM), 256, 0, stream>>>(A, Xt, G1);
    gemm_f32<<<dim3(BC / GBN, NN / GBM), 256, 0, stream>>>(A, G1, G2);
    final_apply<<<NN, 256, 0, stream>>>(X, E, G1, G2, wp, bp, out);
}

// Round 3
// 599.711 us; speedup vs baseline: 2.0064x; 2.0064x over previous
//
#include <hip/hip_runtime.h>

// Problem constants (B=16, N=4096, C=64, O=64, D=16, K=3)
#define NN 4096
#define DD 16
#define BB 16
#define CC 64
#define OO 64
#define BC 1024   // BB*CC

typedef unsigned short u16;
typedef __attribute__((ext_vector_type(8))) short bf16x8;
typedef __attribute__((ext_vector_type(4))) float f32x4;

__device__ __forceinline__ u16 f2bf(float f) {
    unsigned u = __builtin_bit_cast(unsigned, f);
    unsigned r = u + 0x7FFFu + ((u >> 16) & 1u);
    return (u16)(r >> 16);
}
__device__ __forceinline__ float bf2f(u16 h) {
    unsigned u = ((unsigned)h) << 16;
    return __builtin_bit_cast(float, u);
}

// ---------------------------------------------------------------------------
// Kernel 1: A = softmax(relu(E @ E^T), axis=1) -> split bf16 (Ah + Al)
// ---------------------------------------------------------------------------
__global__ __launch_bounds__(256) void softmax_adj(const float* __restrict__ E,
                                                   u16* __restrict__ Ah,
                                                   u16* __restrict__ Al) {
    const int i = blockIdx.x;
    const int t = threadIdx.x;
    __shared__ float esh[DD];
    __shared__ float redm[4], reds[4];
    if (t < DD) esh[t] = E[i * DD + t];
    __syncthreads();
    float er[DD];
#pragma unroll
    for (int d = 0; d < DD; ++d) er[d] = esh[d];

    float v[16];
    float m = 0.0f;  // relu => max >= 0
#pragma unroll
    for (int s = 0; s < 16; ++s) {
        const int j = s * 256 + t;
        const float4* ej = (const float4*)(E + j * DD);
        float4 a0 = ej[0], a1 = ej[1], a2 = ej[2], a3 = ej[3];
        float dot = a0.x * er[0] + a0.y * er[1] + a0.z * er[2] + a0.w * er[3]
                  + a1.x * er[4] + a1.y * er[5] + a1.z * er[6] + a1.w * er[7]
                  + a2.x * er[8] + a2.y * er[9] + a2.z * er[10] + a2.w * er[11]
                  + a3.x * er[12] + a3.y * er[13] + a3.z * er[14] + a3.w * er[15];
        v[s] = fmaxf(dot, 0.0f);
        m = fmaxf(m, v[s]);
    }
#pragma unroll
    for (int off = 1; off < 64; off <<= 1) m = fmaxf(m, __shfl_xor(m, off));
    const int wave = t >> 6, lane = t & 63;
    if (lane == 0) redm[wave] = m;
    __syncthreads();
    m = fmaxf(fmaxf(redm[0], redm[1]), fmaxf(redm[2], redm[3]));

    float sum = 0.0f;
#pragma unroll
    for (int s = 0; s < 16; ++s) {
        v[s] = expf(v[s] - m);
        sum += v[s];
    }
#pragma unroll
    for (int off = 1; off < 64; off <<= 1) sum += __shfl_xor(sum, off);
    if (lane == 0) reds[wave] = sum;
    __syncthreads();
    const float rinv = 1.0f / (reds[0] + reds[1] + reds[2] + reds[3]);
#pragma unroll
    for (int s = 0; s < 16; ++s) {
        const float val = v[s] * rinv;
        const u16 hh = f2bf(val);
        Ah[(size_t)i * NN + s * 256 + t] = hh;
        Al[(size_t)i * NN + s * 256 + t] = f2bf(val - bf2f(hh));
    }
}

// ---------------------------------------------------------------------------
// Kernel 2: transpose+split X [B,N,C] -> Xt_{h,l} [BC=b*64+c][N] bf16
// 64x64 node-tile per block, LDS transpose. grid (64, 16)
// ---------------------------------------------------------------------------
__global__ __launch_bounds__(256) void pack_xt(const float* __restrict__ X,
                                               u16* __restrict__ Xth,
                                               u16* __restrict__ Xtl) {
    const int n0 = blockIdx.x * 64;
    const int b  = blockIdx.y;
    const int t  = threadIdx.x;
    __shared__ float tx[64][68];
    const float* src = X + (size_t)b * (NN * CC) + (size_t)n0 * CC;
#pragma unroll
    for (int l = 0; l < 4; ++l) {
        const int idx = t + l * 256;   // 1024 float4 chunks
        const int r = idx >> 4;
        const int c4 = (idx & 15) * 4;
        float4 v = *(const float4*)(src + r * CC + c4);
        tx[r][c4 + 0] = v.x; tx[r][c4 + 1] = v.y;
        tx[r][c4 + 2] = v.z; tx[r][c4 + 3] = v.w;
    }
    __syncthreads();
#pragma unroll
    for (int l = 0; l < 2; ++l) {
        const int idx = t + l * 256;   // 512 chunks of 8 bf16
        const int c = idx >> 3;
        const int n8 = (idx & 7) * 8;
        unsigned hw[4], lw[4];
#pragma unroll
        for (int jp = 0; jp < 4; ++jp) {
            float v0 = tx[n8 + 2 * jp][c];
            float v1 = tx[n8 + 2 * jp + 1][c];
            u16 h0 = f2bf(v0), h1 = f2bf(v1);
            u16 l0 = f2bf(v0 - bf2f(h0)), l1 = f2bf(v1 - bf2f(h1));
            hw[jp] = (unsigned)h0 | ((unsigned)h1 << 16);
            lw[jp] = (unsigned)l0 | ((unsigned)l1 << 16);
        }
        const size_t off = (size_t)(b * 64 + c) * NN + n0 + n8;
        *(uint4*)(Xth + off) = make_uint4(hw[0], hw[1], hw[2], hw[3]);
        *(uint4*)(Xtl + off) = make_uint4(lw[0], lw[1], lw[2], lw[3]);
    }
}

// ---------------------------------------------------------------------------
// Kernel 3: split-bf16 MFMA GEMM.  C[m][n] = sum_k A[m][k] * Bt[n][k]
//   A: [4096][4096] bf16 hi/lo row-major; Bt: [1024][4096] bf16 hi/lo.
//   3-product split: AhBh + AhBl + AlBh, f32 MFMA accumulate.
//   BM=BN=128, BK=32, 256 thr (4 waves, 64x64/wave), dbuf LDS, gload_lds w16.
//   EPI=0: write Cf f32 [M][1024] + C^T bf16 hi/lo [1024][M]   (GEMM1)
//   EPI=1: write Cf only                                        (GEMM2)
// ---------------------------------------------------------------------------
#define GLOAD16(g, l) __builtin_amdgcn_global_load_lds( \
    (const __attribute__((address_space(1))) unsigned int*)(g), \
    (__attribute__((address_space(3))) unsigned int*)(l), 16, 0, 0)

template<int EPI>
__global__ __launch_bounds__(256) void gemm_split(
    const u16* __restrict__ Ah, const u16* __restrict__ Al,
    const u16* __restrict__ Bh, const u16* __restrict__ Bl,
    float* __restrict__ Cf, u16* __restrict__ Cth, u16* __restrict__ Ctl)
{
    __shared__ uint4 lds[2][4][512];   // [buf][Ah,Al,Bh,Bl][128 rows x 4 slots]
    const int t = threadIdx.x;
    const int row0 = blockIdx.y * 128;
    const int col0 = blockIdx.x * 128;

    // staging geometry: chunk j -> row=j>>2, slot=j&3; source col16 inverse-swizzled
    const int j0 = t, j1 = t + 256;
    const int r0 = j0 >> 2, r1 = j1 >> 2;
    const int s0 = (j0 & 3) ^ ((j0 >> 3) & 3);
    const int s1 = (j1 & 3) ^ ((j1 >> 3) & 3);
    const size_t aoff0 = (size_t)(row0 + r0) * NN + 8 * s0;
    const size_t aoff1 = (size_t)(row0 + r1) * NN + 8 * s1;
    const size_t boff0 = (size_t)(col0 + r0) * NN + 8 * s0;
    const size_t boff1 = (size_t)(col0 + r1) * NN + 8 * s1;

    const int lane = t & 63, g = lane >> 4, lr = lane & 15;
    const int wm = t >> 7, wn = (t >> 6) & 1;
    int ia[4], ib[4];
#pragma unroll
    for (int i = 0; i < 4; ++i) {
        const int ra = wm * 64 + 16 * i + lr;
        ia[i] = ra * 4 + (g ^ ((ra >> 1) & 3));
        const int rb = wn * 64 + 16 * i + lr;
        ib[i] = rb * 4 + (g ^ ((rb >> 1) & 3));
    }

    f32x4 acc[4][4];
    const f32x4 zz = {0.f, 0.f, 0.f, 0.f};
#pragma unroll
    for (int i = 0; i < 4; ++i)
#pragma unroll
        for (int p = 0; p < 4; ++p) acc[i][p] = zz;

#define STAGE(bf, kt) do { \
        GLOAD16(Ah + aoff0 + (kt), &lds[bf][0][j0]); \
        GLOAD16(Ah + aoff1 + (kt), &lds[bf][0][j1]); \
        GLOAD16(Al + aoff0 + (kt), &lds[bf][1][j0]); \
        GLOAD16(Al + aoff1 + (kt), &lds[bf][1][j1]); \
        GLOAD16(Bh + boff0 + (kt), &lds[bf][2][j0]); \
        GLOAD16(Bh + boff1 + (kt), &lds[bf][2][j1]); \
        GLOAD16(Bl + boff0 + (kt), &lds[bf][3][j0]); \
        GLOAD16(Bl + boff1 + (kt), &lds[bf][3][j1]); \
    } while (0)

    STAGE(0, 0);
    __syncthreads();   // drains vmcnt+lgkmcnt before barrier (m97 semantics)

#pragma unroll 2
    for (int kt = 0; kt < NN; kt += 32) {
        const int cur = (kt >> 5) & 1;
        if (kt + 32 < NN) STAGE(cur ^ 1, kt + 32);

        bf16x8 ah[4], al[4], bh[4], bl[4];
#pragma unroll
        for (int i = 0; i < 4; ++i) {
            ah[i] = *(const bf16x8*)&lds[cur][0][ia[i]];
            al[i] = *(const bf16x8*)&lds[cur][1][ia[i]];
            bh[i] = *(const bf16x8*)&lds[cur][2][ib[i]];
            bl[i] = *(const bf16x8*)&lds[cur][3][ib[i]];
        }
#pragma unroll
        for (int i = 0; i < 4; ++i)
#pragma unroll
            for (int p = 0; p < 4; ++p) {
                acc[i][p] = __builtin_amdgcn_mfma_f32_16x16x32_bf16(ah[i], bh[p], acc[i][p], 0, 0, 0);
                acc[i][p] = __builtin_amdgcn_mfma_f32_16x16x32_bf16(ah[i], bl[p], acc[i][p], 0, 0, 0);
                acc[i][p] = __builtin_amdgcn_mfma_f32_16x16x32_bf16(al[i], bh[p], acc[i][p], 0, 0, 0);
            }
        __syncthreads();
    }

    // epilogue: C/D layout col=lane&15, row=(lane>>4)*4+q  [m89 verified]
#pragma unroll
    for (int i = 0; i < 4; ++i)
#pragma unroll
        for (int p = 0; p < 4; ++p) {
            const int mb = row0 + wm * 64 + 16 * i + g * 4;
            const int c  = col0 + wn * 64 + 16 * p + lr;
#pragma unroll
            for (int q = 0; q < 4; ++q)
                Cf[(size_t)(mb + q) * BC + c] = acc[i][p][q];
            if (EPI == 0) {
                u16 h[4], lo[4];
#pragma unroll
                for (int q = 0; q < 4; ++q) {
                    const float v = acc[i][p][q];
                    h[q]  = f2bf(v);
                    lo[q] = f2bf(v - bf2f(h[q]));
                }
                const size_t toff = (size_t)c * NN + mb;
                *(uint2*)(Cth + toff) =
                    make_uint2((unsigned)h[0] | ((unsigned)h[1] << 16),
                               (unsigned)h[2] | ((unsigned)h[3] << 16));
                *(uint2*)(Ctl + toff) =
                    make_uint2((unsigned)lo[0] | ((unsigned)lo[1] << 16),
                               (unsigned)lo[2] | ((unsigned)lo[3] << 16));
            }
        }
#undef STAGE
}

// ---------------------------------------------------------------------------
// Kernel 4: per-node W build + apply + bias (unchanged; reads f32 G1/G2)
// ---------------------------------------------------------------------------
__global__ __launch_bounds__(256) void final_apply(const float* __restrict__ X,
                                                   const float* __restrict__ E,
                                                   const float* __restrict__ G1,
                                                   const float* __restrict__ G2,
                                                   const float* __restrict__ wp,
                                                   const float* __restrict__ bp,
                                                   float* __restrict__ out) {
    const int n = blockIdx.x;
    const int t = threadIdx.x;
    __shared__ float W[3 * CC * OO];   // 48KB
    __shared__ float xg[3][BC];        // 12KB
    __shared__ float esh[DD];
    if (t < DD) esh[t] = E[n * DD + t];
#pragma unroll
    for (int l = 0; l < 4; ++l) {
        const int idx = t + l * 256;
        const int b = idx >> 6;
        const int i = idx & 63;
        const float xs = X[(size_t)b * (NN * CC) + (size_t)n * CC + i];
        const float g1 = G1[(size_t)n * BC + idx];
        const float g2 = G2[(size_t)n * BC + idx];
        xg[0][idx] = xs;
        xg[1][idx] = g1;
        xg[2][idx] = 2.0f * g2 - xs;
    }
    __syncthreads();
    float er[DD];
#pragma unroll
    for (int d = 0; d < DD; ++d) er[d] = esh[d];

    const float4* wp4 = (const float4*)wp;
#pragma unroll
    for (int l = 0; l < 12; ++l) {
        const int w4 = t + l * 256;
        float4 a = make_float4(0.f, 0.f, 0.f, 0.f);
#pragma unroll
        for (int d = 0; d < DD; ++d) {
            float4 v = wp4[d * 3072 + w4];
            a.x += er[d] * v.x;
            a.y += er[d] * v.y;
            a.z += er[d] * v.z;
            a.w += er[d] * v.w;
        }
        *(float4*)&W[w4 * 4] = a;
    }
    __syncthreads();

#pragma unroll
    for (int p = 0; p < 4; ++p) {
        const int idx2 = t + p * 256;
        const int b = idx2 >> 6;
        const int o = idx2 & 63;
        float acc = 0.0f;
#pragma unroll
        for (int d = 0; d < DD; ++d) acc += er[d] * bp[d * OO + o];
#pragma unroll
        for (int k = 0; k < 3; ++k) {
            const float* wk = &W[k * (CC * OO) + o];
            const float* xk = &xg[k][b * CC];
#pragma unroll 16
            for (int i = 0; i < CC; ++i) acc += xk[i] * wk[i * OO];
        }
        out[(size_t)b * (NN * OO) + (size_t)n * OO + o] = acc;
    }
}

// ---------------------------------------------------------------------------
extern "C" void kernel_launch(void* const* d_in, const int* in_sizes, int n_in,
                              void* d_out, int out_size, void* d_ws, size_t ws_size,
                              hipStream_t stream) {
    const float* X  = (const float*)d_in[0];   // [16,4096,64]
    const float* E  = (const float*)d_in[1];   // [4096,16]
    const float* wp = (const float*)d_in[3];   // [16,3,64,64]
    const float* bp = (const float*)d_in[4];   // [16,64]
    float* out = (float*)d_out;                // [16,4096,64]

    // ws layout (112 MB):
    u16* Ah   = (u16*)d_ws;                        // 32 MB
    u16* Al   = Ah   + (size_t)NN * NN;            // 32 MB
    u16* Xth  = Al   + (size_t)NN * NN;            //  8 MB
    u16* Xtl  = Xth  + (size_t)BC * NN;            //  8 MB
    u16* G1th = Xtl  + (size_t)BC * NN;            //  8 MB
    u16* G1tl = G1th + (size_t)BC * NN;            //  8 MB
    float* G1f = (float*)(G1tl + (size_t)BC * NN); // 16 MB
    float* G2f = (float*)Xth;                      // overlay: Xt dead after GEMM1

    softmax_adj<<<NN, 256, 0, stream>>>(E, Ah, Al);
    pack_xt<<<dim3(NN / 64, BB), 256, 0, stream>>>(X, Xth, Xtl);
    gemm_split<0><<<dim3(BC / 128, NN / 128), 256, 0, stream>>>(
        Ah, Al, Xth, Xtl, G1f, G1th, G1tl);
    gemm_split<1><<<dim3(BC / 128, NN / 128), 256, 0, stream>>>(
        Ah, Al, G1th, G1tl, G2f, nullptr, nullptr);
    final_apply<<<NN, 256, 0, stream>>>(X, E, G1f, G2f, wp, bp, out);
}